// Round 7
// baseline (223.745 us; speedup 1.0000x reference)
//
#include <hip/hip_runtime.h>
#include <cstddef>
#include <cstdint>

#define T_SEQ 2048
#define EMB_D 2048
#define HD_D  128

typedef __attribute__((ext_vector_type(8))) short short8;
typedef __attribute__((ext_vector_type(4))) float f32x4;
typedef __attribute__((ext_vector_type(4))) unsigned short ushort4v;
typedef __attribute__((ext_vector_type(8))) unsigned short ushort8v;
typedef __attribute__((ext_vector_type(2))) unsigned int uint2v;

static __device__ __forceinline__ unsigned short f2bf_rne(float f) {
    union { float f; unsigned u; } v; v.f = f;
    unsigned r = v.u + 0x7fffu + ((v.u >> 16) & 1u);
    return (unsigned short)(r >> 16);
}
static __device__ __forceinline__ unsigned short f2bf_fast(float f) {
    union { float f; unsigned u; } v; v.f = f;
    return (unsigned short)((v.u + 0x8000u) >> 16);
}
static __device__ __forceinline__ float bf2f(unsigned short h) {
    union { unsigned u; float f; } v; v.u = ((unsigned)h) << 16;
    return v.f;
}
// pack two fp32 -> packed bf16 pair (round-half-up) in 3 VALU
static __device__ __forceinline__ unsigned pk2(float a, float b) {
    union { float f; unsigned u; } x, y; x.f = a; y.f = b;
    return __builtin_amdgcn_perm(y.u + 0x8000u, x.u + 0x8000u, 0x07060302);
}
#define EXP2F(x) __builtin_amdgcn_exp2f(x)

// ---------------------------------------------------------------------------
// Kernel 0: coalesced transpose + bf16 convert: Wt[w][n][k] = W_w[k][n]
//   (R12 coalesced-store version, frozen)
// ---------------------------------------------------------------------------
__global__ __launch_bounds__(256) void prep_weights(
    const float* __restrict__ Wq, const float* __restrict__ Wk,
    const float* __restrict__ Wv, unsigned short* __restrict__ Wt)
{
    __shared__ __attribute__((aligned(16))) unsigned short tw[64 * 132];
    const int w = blockIdx.y;
    const int k0 = blockIdx.x * 64;
    const float* W = (w == 0) ? Wq : (w == 1) ? Wk : Wv;
    const int tid = threadIdx.x;
#pragma unroll
    for (int p = 0; p < 8; p++) {
        const int f = p * 256 + tid;        // float4 index over 64x32
        const int row = f >> 5, c4 = f & 31;
        const float4 v = *(const float4*)&W[(size_t)(k0 + row) * HD_D + c4 * 4];
        ushort4v h = { f2bf_rne(v.x), f2bf_rne(v.y), f2bf_rne(v.z), f2bf_rne(v.w) };
        *(ushort4v*)&tw[row * 132 + c4 * 4] = h;
    }
    __syncthreads();
    const int kk = (tid & 7) * 8;           // 8 k per thread
#pragma unroll
    for (int p = 0; p < 4; p++) {
        const int n = p * 32 + (tid >> 3);  // 32 n-rows per pass
        ushort8v o;
#pragma unroll
        for (int jj = 0; jj < 8; jj++) o[jj] = tw[(kk + jj) * 132 + n];
        *(ushort8v*)&Wt[(size_t)w * (HD_D * EMB_D) + (size_t)n * EMB_D + k0 + kk] = o;
    }
}

// ---------------------------------------------------------------------------
// Kernel 1: FUSED QKV projection + RoPE — R20: x ONCE + direct-L2 W.
//   R19 decomposition: 7110 cyc/phase = LDS port (~2880) + x delivery at the
//   HBM/L3 stream ceiling (~9-10 B/cyc/CU). The 4x x duplication (268 MB)
//   at ~6 TB/s IS the ~46 us floor every variant hit. R16 failed on
//   concurrency (1 domain), not on the traffic theory.
//   R20 structure:
//     * BM=16, BN=384 (ALL cols/block) -> x read ONCE (67 MB, ~11 us).
//       Grid 512 = 2 blk/CU (2 domains), 512 thr = 8 waves = 16 waves/CU.
//     * each wave owns a 48-col group: wave tile 16x48, acc[3] — R17's
//       proven per-wave code minus the i loop. ks=0..3 ascending ->
//       bit-identical accumulation.
//     * W fragments DIRECT global->register (no W LDS, no race surface):
//       12 short8/lane/phase from L2-resident Wt (805 MB total but L2-class
//       ~56 B/cyc/CU, overlaps the x stream). Single reg set, refilled
//       AFTER its consuming COMPUTE (WAR order); ~1 phase flight.
//     * only x staged: LDS 8 KB (2 x 4 KB bf16), BK=128 -> 16 phases,
//       stage = one 8-B write/thread; same swizzle + lgkm-only barrier +
//       2-set register flight discipline as R14/R19.
// ---------------------------------------------------------------------------
__global__ __launch_bounds__(512, 4) void qkv_fused(
    const float* __restrict__ x, const unsigned short* __restrict__ Wt,
    const float* __restrict__ rcos, const float* __restrict__ rsin,
    unsigned short* __restrict__ Qb, unsigned short* __restrict__ Kb,
    unsigned short* __restrict__ Vt)
{
    __shared__ __attribute__((aligned(16))) unsigned short xsm[2][16 * 128]; // 2 x 4 KB
    const int L = blockIdx.x;
    const int m0 = ((L & 7) * 64 + (L >> 3)) * 16;  // XCD-bijective (512 % 8 == 0)
    const int tid = threadIdx.x;
    const int lane = tid & 63, wn = tid >> 6;       // 8 waves = 8 col-groups of 48
    const int l15 = lane & 15, lq = lane >> 4;

    // ---- x: 16 rows x 128 f32 per K-tile; 512 thr -> 1 float4 each (coalesced)
    const int xrow = tid >> 5, xc4 = tid & 31;
    const float* xsrc = x + (size_t)(m0 + xrow) * EMB_D + xc4 * 4;
    // LDS row = 256 B (128 bf16), 16-B chunks, swizzle chunk ^= (row&7)
    const int xw = xrow * 256 + (((xc4 >> 1) ^ (xrow & 7)) << 4) + (xc4 & 1) * 8;

    // ---- A-frag read offsets (all waves read the same 16 rows: broadcast)
    int ra[4];
#pragma unroll
    for (int ks = 0; ks < 4; ks++)
        ra[ks] = l15 * 256 + (((ks * 4 + lq) ^ (l15 & 7)) << 4);

    // ---- W direct pointers: row n = wn*48 + jj*16 + l15, k = k0 + ks*32 + lq*8
    //      (ks offsets 64/128/192 B fold into the 13-bit global imm)
    const unsigned short* wptr[3];
#pragma unroll
    for (int jj = 0; jj < 3; jj++)
        wptr[jj] = Wt + (size_t)(wn * 48 + jj * 16 + l15) * EMB_D + lq * 8;

    f32x4 acc[3];
#pragma unroll
    for (int j = 0; j < 3; j++) acc[j] = (f32x4){0.f, 0.f, 0.f, 0.f};

    float4 xr[2];        // two named x sets -> 2-phase load flight
    short8 wr[3][4];     // single W set (48 VGPR), refilled after consumption

#define LOADX(S, K) do { xr[S] = *(const float4*)(xsrc + (K)); } while (0)

#define LOADW(K)                                                               \
    do {                                                                       \
        _Pragma("unroll")                                                      \
        for (int jj = 0; jj < 3; jj++)                                         \
            _Pragma("unroll")                                                  \
            for (int ks = 0; ks < 4; ks++)                                     \
                wr[jj][ks] = *(const short8*)(wptr[jj] + (K) + ks * 32);       \
    } while (0)

#define STAGE(S, BUF)                                                          \
    do {                                                                       \
        uint2v u;                                                              \
        u.x = pk2(xr[S].x, xr[S].y);                                           \
        u.y = pk2(xr[S].z, xr[S].w);                                           \
        *(uint2v*)((char*)&xsm[BUF][0] + xw) = u;                              \
    } while (0)

#define COMPUTE(BUF)                                                           \
    do {                                                                       \
        const char* xb = (const char*)&xsm[BUF][0];                            \
        short8 Af[4];                                                          \
        _Pragma("unroll")                                                      \
        for (int ks = 0; ks < 4; ks++)                                         \
            Af[ks] = *(const short8*)(xb + ra[ks]);                            \
        __builtin_amdgcn_s_setprio(1);                                         \
        _Pragma("unroll")                                                      \
        for (int ks = 0; ks < 4; ks++)                                         \
            _Pragma("unroll")                                                  \
            for (int jj = 0; jj < 3; jj++)                                     \
                acc[jj] = __builtin_amdgcn_mfma_f32_16x16x32_bf16(             \
                    Af[ks], wr[jj][ks], acc[jj], 0, 0, 0);                     \
        __builtin_amdgcn_s_setprio(0);                                         \
    } while (0)

// barrier: drain own ds ops only (x-stage visibility); global loads stay in
// flight across it ("memory" clobber pins load issue inside its phase).
#define BARX() asm volatile("s_waitcnt lgkmcnt(0)\n\ts_barrier" ::: "memory")

    // ---- prologue: x k0->set0, W k0, x k1->set1, stage k0, x k2->set0
    LOADX(0, 0);
    LOADW(0);
    LOADX(1, 128);
    STAGE(0, 0);          // counted vmcnt wait for set0 only
    LOADX(0, 256);

    // ---- main loop: phase p = {BAR; stage k(p+1); loadX k(p+3);
    //      compute k(p) [uses wr loaded at end of p-1]; loadW k(p+1)}
#pragma clang loop unroll(disable)
    for (int j = 0; j < 12; j += 2) {
        BARX(); STAGE(1, 1); LOADX(1, (j + 3) * 128); COMPUTE(0); LOADW((j + 1) * 128);
        BARX(); STAGE(0, 0); LOADX(0, (j + 4) * 128); COMPUTE(1); LOADW((j + 2) * 128);
    }
    // ---- tail: phases 12..15
    BARX(); STAGE(1, 1); LOADX(1, 15 * 128); COMPUTE(0); LOADW(13 * 128);  // p=12
    BARX(); STAGE(0, 0);                     COMPUTE(1); LOADW(14 * 128);  // p=13
    BARX(); STAGE(1, 1);                     COMPUTE(0); LOADW(15 * 128);  // p=14
    BARX();                                  COMPUTE(1);                   // p=15

#undef LOADX
#undef LOADW
#undef STAGE
#undef COMPUTE
#undef BARX

    const float qscale = 0.08838834764831845f * 1.4426950408889634f; // 1/sqrt(128)*log2(e)
#pragma unroll
    for (int r = 0; r < 4; r++) {
        const int row = m0 + lq * 4 + r;   // b*T + t
        const int t = row & (T_SEQ - 1);
        const int bb = row >> 11;
#pragma unroll
        for (int j = 0; j < 3; j++) {
            const int col = wn * 48 + j * 16 + l15;
            const int mat = col >> 7, mcol = col & 127;
            const float v = acc[j][r];
            if (mat == 2) {
                Vt[((size_t)bb * HD_D + mcol) * T_SEQ + t] = f2bf_rne(v);
            } else {
                const int ip = mcol >> 1;
                const float c = rcos[t * 64 + ip];
                const float s2 = rsin[t * 64 + ip];
                const float pv = __shfl_xor(v, 1);
                float rv = (mcol & 1) ? (pv * s2 + v * c) : (v * c - pv * s2);
                if (mat == 0) {
                    rv *= qscale;
                    Qb[(size_t)row * HD_D + mcol] = f2bf_rne(rv);
                } else {
                    Kb[(size_t)row * HD_D + mcol] = f2bf_rne(rv);
                }
            }
        }
    }
}

// ---------------------------------------------------------------------------
// Kernel 2: flash attention — R18 version, frozen (QBLK=32, K/V traffic
//   halved; single-stream c-loop, bit-identical accumulation).
// ---------------------------------------------------------------------------
__global__ __launch_bounds__(256, 2) void attn(
    const unsigned short* __restrict__ Qb, const unsigned short* __restrict__ Kb,
    const unsigned short* __restrict__ Vt, float* __restrict__ O0,
    unsigned short* __restrict__ O1, float* __restrict__ Lp)
{
    __shared__ __attribute__((aligned(16))) unsigned short O_s[4][32 * 128];   // 32 KB
    __shared__ __attribute__((aligned(16))) unsigned short P_s[4][32 * 40];    // 10 KB
    __shared__ float l_s[4][32];

    const int tid = threadIdx.x;
    const int lane = tid & 63, wave = tid >> 6;
    const int l15 = lane & 15, lq = lane >> 4;
    const int kf = lq * 8;

    const int L = blockIdx.x;
    const int g = L & 1;                         // k-group
    const int b = (L >> 1) & 3;
    const int q0 = (63 - (L >> 3)) * 32;         // heavy q-blocks first
    const int kend = q0 + 32;
    const float M2 = 16.0f;                      // static max (exp2 domain)

    const unsigned short* Qp = Qb + (size_t)(b * T_SEQ + q0) * HD_D;
    short8 aQ[2][4];
#pragma unroll
    for (int i = 0; i < 2; i++)
#pragma unroll
        for (int d = 0; d < 4; d++)
            aQ[i][d] = *(const short8*)&Qp[(size_t)(i * 16 + l15) * HD_D + d * 32 + kf];

    f32x4 acc[2][8];
#pragma unroll
    for (int i = 0; i < 2; i++)
#pragma unroll
        for (int d = 0; d < 8; d++) acc[i][d] = (f32x4){0.f, 0.f, 0.f, 0.f};
    float l_r[2][4] = {{0.f, 0.f, 0.f, 0.f}, {0.f, 0.f, 0.f, 0.f}};

    const unsigned short* Kbase = Kb + (size_t)b * T_SEQ * HD_D;
    const unsigned short* Vbase = Vt + (size_t)b * HD_D * T_SEQ;
    unsigned short* Pw = &P_s[wave][0];

    for (int c = 2 * wave + g; c * 32 < kend; c += 8) {
        const int kA = c * 32;
        const unsigned short* Kp = Kbase + (size_t)kA * HD_D;
        short8 KA[8];
#pragma unroll
        for (int d = 0; d < 4; d++)
#pragma unroll
            for (int n = 0; n < 2; n++)
                KA[d * 2 + n] = *(const short8*)&Kp[(size_t)(n * 16 + l15) * HD_D + d * 32 + kf];

        f32x4 sc[2][2];
#pragma unroll
        for (int i = 0; i < 2; i++)
#pragma unroll
            for (int n = 0; n < 2; n++) sc[i][n] = (f32x4){0.f, 0.f, 0.f, 0.f};
#pragma unroll
        for (int d = 0; d < 4; d++)
#pragma unroll
            for (int i = 0; i < 2; i++)
#pragma unroll
                for (int n = 0; n < 2; n++)
                    sc[i][n] = __builtin_amdgcn_mfma_f32_16x16x32_bf16(
                        aQ[i][d], KA[d * 2 + n], sc[i][n], 0, 0, 0);

        short8 VA[8];
#pragma unroll
        for (int d = 0; d < 8; d++)
            VA[d] = *(const short8*)&Vbase[(size_t)(d * 16 + l15) * T_SEQ + kA + kf];

#pragma unroll
        for (int i = 0; i < 2; i++)
#pragma unroll
            for (int r = 0; r < 4; r++) {
                const int q = q0 + i * 16 + lq * 4 + r;
                const float p0 = ((kA + l15)      <= q) ? EXP2F(sc[i][0][r] - M2) : 0.f;
                const float p1 = ((kA + 16 + l15) <= q) ? EXP2F(sc[i][1][r] - M2) : 0.f;
                l_r[i][r] += p0 + p1;
                const int prow = (i * 16 + lq * 4 + r) * 40;
                Pw[prow + l15]      = f2bf_fast(p0);
                Pw[prow + 16 + l15] = f2bf_fast(p1);
            }
        short8 pA[2];
#pragma unroll
        for (int i = 0; i < 2; i++)
            pA[i] = *(const short8*)&Pw[(i * 16 + l15) * 40 + kf];
#pragma unroll
        for (int i = 0; i < 2; i++)
#pragma unroll
            for (int d = 0; d < 8; d++)
                acc[i][d] = __builtin_amdgcn_mfma_f32_16x16x32_bf16(pA[i], VA[d], acc[i][d], 0, 0, 0);
    }

#pragma unroll
    for (int i = 0; i < 2; i++)
#pragma unroll
        for (int r = 0; r < 4; r++) {
            float lr = l_r[i][r];
            lr += __shfl_xor(lr, 1);
            lr += __shfl_xor(lr, 2);
            lr += __shfl_xor(lr, 4);
            lr += __shfl_xor(lr, 8);
            if (l15 == 0) l_s[wave][i * 16 + lq * 4 + r] = lr;
#pragma unroll
            for (int d = 0; d < 8; d++)
                O_s[wave][(i * 16 + lq * 4 + r) * 128 + d * 16 + l15] = f2bf_fast(acc[i][d][r]);
        }
    __syncthreads();

#pragma unroll
    for (int pass = 0; pass < 2; pass++) {
        const int row = pass * 16 + (tid >> 4);
        const int dc = (tid & 15) * 8;
        const float lt = l_s[0][row] + l_s[1][row] + l_s[2][row] + l_s[3][row];
        float o[8];
#pragma unroll
        for (int k = 0; k < 8; k++) o[k] = 0.f;
#pragma unroll
        for (int w2 = 0; w2 < 4; w2++) {
            const ushort8v pv = *(const ushort8v*)&O_s[w2][row * 128 + dc];
#pragma unroll
            for (int k = 0; k < 8; k++) o[k] += bf2f(pv[k]);
        }
        const size_t grow = (size_t)(b * T_SEQ + q0 + row);
        if (g == 0) {
            float* op = O0 + grow * HD_D + dc;
#pragma unroll
            for (int k = 0; k < 8; k++) op[k] = o[k];
        } else {
            ushort8v h;
#pragma unroll
            for (int k = 0; k < 8; k++) h[k] = f2bf_fast(o[k]);
            *(ushort8v*)&O1[grow * HD_D + dc] = h;
        }
        if ((tid & 15) == 0) Lp[g * 8192 + grow] = lt;
    }
}

// ---------------------------------------------------------------------------
// Kernel 3: combine the two k-group partials: out = (O0 + O1) / (l0 + l1)
// ---------------------------------------------------------------------------
__global__ __launch_bounds__(256) void attn_merge(
    float* __restrict__ out, const unsigned short* __restrict__ O1,
    const float* __restrict__ Lp)
{
    const int idx = blockIdx.x * 256 + threadIdx.x;   // f32x4 index (262144)
    const int row = idx >> 5;                          // 32 f32x4 per row
    f32x4 a = ((f32x4*)out)[idx];
    const ushort4v h = ((const ushort4v*)O1)[idx];
    f32x4 bv = { bf2f(h.x), bf2f(h.y), bf2f(h.z), bf2f(h.w) };
    const float inv = 1.0f / (Lp[row] + Lp[8192 + row]);
    ((f32x4*)out)[idx] = (a + bv) * inv;
}

// ---------------------------------------------------------------------------
extern "C" void kernel_launch(void* const* d_in, const int* in_sizes, int n_in,
                              void* d_out, int out_size, void* d_ws, size_t ws_size,
                              hipStream_t stream)
{
    (void)in_sizes; (void)n_in; (void)out_size; (void)ws_size;
    const float* x  = (const float*)d_in[0];
    const float* Wq = (const float*)d_in[1];
    const float* Wk = (const float*)d_in[2];
    const float* Wv = (const float*)d_in[3];
    const float* rc = (const float*)d_in[4];
    const float* rs = (const float*)d_in[5];
    // d_in[6] = additive causal mask: handled analytically, not read.
    float* out = (float*)d_out;

    char* ws = (char*)d_ws;
    unsigned short* Wt = (unsigned short*)(ws);                    // 1,572,864 B
    unsigned short* Qb = (unsigned short*)(ws + 1572864);          // 2,097,152 B
    unsigned short* Kb = (unsigned short*)(ws + 3670016);          // 2,097,152 B
    unsigned short* Vt = (unsigned short*)(ws + 5767168);          // 2,097,152 B
    unsigned short* O1 = (unsigned short*)(ws + 7864320);          // 2,097,152 B
    float*          Lp = (float*)(ws + 9961472);                   //    65,536 B

    prep_weights<<<dim3(32, 3), 256, 0, stream>>>(Wq, Wk, Wv, Wt);
    qkv_fused   <<<dim3(512),   512, 0, stream>>>(x, Wt, rc, rs, Qb, Kb, Vt);
    attn        <<<dim3(512),   256, 0, stream>>>(Qb, Kb, Vt, out, O1, Lp);
    attn_merge  <<<dim3(1024),  256, 0, stream>>>(out, O1, Lp);
}

// Round 8
// 171.976 us; speedup vs baseline: 1.3010x; 1.3010x over previous
//
#include <hip/hip_runtime.h>
#include <cstddef>
#include <cstdint>

#define T_SEQ 2048
#define EMB_D 2048
#define HD_D  128

typedef __attribute__((ext_vector_type(8))) short short8;
typedef __attribute__((ext_vector_type(4))) float f32x4;
typedef __attribute__((ext_vector_type(4))) unsigned short ushort4v;
typedef __attribute__((ext_vector_type(8))) unsigned short ushort8v;
typedef __attribute__((ext_vector_type(2))) unsigned int uint2v;

static __device__ __forceinline__ unsigned short f2bf_rne(float f) {
    union { float f; unsigned u; } v; v.f = f;
    unsigned r = v.u + 0x7fffu + ((v.u >> 16) & 1u);
    return (unsigned short)(r >> 16);
}
static __device__ __forceinline__ unsigned short f2bf_fast(float f) {
    union { float f; unsigned u; } v; v.f = f;
    return (unsigned short)((v.u + 0x8000u) >> 16);
}
static __device__ __forceinline__ float bf2f(unsigned short h) {
    union { unsigned u; float f; } v; v.u = ((unsigned)h) << 16;
    return v.f;
}
// pack two fp32 -> packed bf16 pair (round-half-up) in 3 VALU
static __device__ __forceinline__ unsigned pk2(float a, float b) {
    union { float f; unsigned u; } x, y; x.f = a; y.f = b;
    return __builtin_amdgcn_perm(y.u + 0x8000u, x.u + 0x8000u, 0x07060302);
}
#define EXP2F(x) __builtin_amdgcn_exp2f(x)

// ---------------------------------------------------------------------------
// Kernel 0: coalesced transpose + bf16 convert: Wt[w][n][k] = W_w[k][n]
//   (R12 coalesced-store version, frozen)
// ---------------------------------------------------------------------------
__global__ __launch_bounds__(256) void prep_weights(
    const float* __restrict__ Wq, const float* __restrict__ Wk,
    const float* __restrict__ Wv, unsigned short* __restrict__ Wt)
{
    __shared__ __attribute__((aligned(16))) unsigned short tw[64 * 132];
    const int w = blockIdx.y;
    const int k0 = blockIdx.x * 64;
    const float* W = (w == 0) ? Wq : (w == 1) ? Wk : Wv;
    const int tid = threadIdx.x;
#pragma unroll
    for (int p = 0; p < 8; p++) {
        const int f = p * 256 + tid;        // float4 index over 64x32
        const int row = f >> 5, c4 = f & 31;
        const float4 v = *(const float4*)&W[(size_t)(k0 + row) * HD_D + c4 * 4];
        ushort4v h = { f2bf_rne(v.x), f2bf_rne(v.y), f2bf_rne(v.z), f2bf_rne(v.w) };
        *(ushort4v*)&tw[row * 132 + c4 * 4] = h;
    }
    __syncthreads();
    const int kk = (tid & 7) * 8;           // 8 k per thread
#pragma unroll
    for (int p = 0; p < 4; p++) {
        const int n = p * 32 + (tid >> 3);  // 32 n-rows per pass
        ushort8v o;
#pragma unroll
        for (int jj = 0; jj < 8; jj++) o[jj] = tw[(kk + jj) * 132 + n];
        *(ushort8v*)&Wt[(size_t)w * (HD_D * EMB_D) + (size_t)n * EMB_D + k0 + kk] = o;
    }
}

// ---------------------------------------------------------------------------
// Kernel 1: FUSED QKV projection + RoPE — R21 = R14 VERBATIM (best measured:
//   46.4 us, VGPR 88, 0 bank conflicts).
//   Model closed over R14..R20: delivered bytes ~5-5.5 TB/s per barrier
//   domain, max 2 useful domains/CU; min traffic at grid>=512 is 469 MB
//   (BM64/BN96). 469 MB / 10.1 TB/s = 46 us = R14's measurement. All morphs
//   (R16 1-domain, R17 2xW, R18 BN192, R19 BK128, R20 direct-W) confirmed
//   the balance from different directions. qkv parked at structure ceiling.
// ---------------------------------------------------------------------------
__global__ __launch_bounds__(256, 2) void qkv_fused(
    const float* __restrict__ x, const unsigned short* __restrict__ Wt,
    const float* __restrict__ rcos, const float* __restrict__ rsin,
    unsigned short* __restrict__ Qb, unsigned short* __restrict__ Kb,
    unsigned short* __restrict__ Vt)
{
    __shared__ __attribute__((aligned(16))) unsigned short xsm[2][64 * 64];  // 2 x 8 KB (bf16)
    __shared__ __attribute__((aligned(16))) unsigned short wsm[2][96 * 64];  // 2 x 12 KB
    const int L = blockIdx.x;
    const int xcd = L & 7, s = L >> 3;
    const int ng = s & 3;                       // column group (96 cols)
    const int m0 = (xcd * 16 + (s >> 2)) * 64;  // 128 m-tiles spread across XCDs
    const int tid = threadIdx.x;
    const int lane = tid & 63, wave = tid >> 6;
    const int wm = wave >> 1, wn = wave & 1;    // 2x2 wave grid: 32 rows x 48 cols
    const int l15 = lane & 15, lq = lane >> 4;

    // ---- global sources: LINEAR addressing (fully coalesced)
    const int xrow = tid >> 4, xc = tid & 15;   // p adds 16 rows
    const float* xsrc = x + (size_t)(m0 + xrow) * EMB_D + xc * 4;
    const int wrow = tid >> 3, wc = tid & 7;    // p adds 32 rows
    const unsigned short* wsrc = Wt + (size_t)(ng * 96 + wrow) * EMB_D + wc * 8;

    // ---- LDS write offsets (bytes). Row = 128 B (64 bf16), 8 chunks of 16 B,
    //      swizzle chunk ^= (row&7). p-steps are multiples of 8 rows so the
    //      swizzle term is p-invariant.
    const int xw  = xrow * 128 + (((xc >> 1) ^ (xrow & 7)) << 4) + (xc & 1) * 8; // + p*2048
    const int wwo = wrow * 128 + ((wc ^ (wrow & 7)) << 4);                        // + p*4096

    // ---- fragment read offsets (bytes), same swizzle
    int ra[2][2], rb[3][2];
#pragma unroll
    for (int i = 0; i < 2; i++)
#pragma unroll
        for (int ks = 0; ks < 2; ks++) {
            const int row = wm * 32 + i * 16 + l15;
            ra[i][ks] = row * 128 + (((ks * 4 + lq) ^ (row & 7)) << 4);
        }
#pragma unroll
    for (int jj = 0; jj < 3; jj++)
#pragma unroll
        for (int ks = 0; ks < 2; ks++) {
            const int row = wn * 48 + jj * 16 + l15;
            rb[jj][ks] = row * 128 + (((ks * 4 + lq) ^ (row & 7)) << 4);
        }

    f32x4 acc[2][3];
#pragma unroll
    for (int i = 0; i < 2; i++)
#pragma unroll
        for (int j = 0; j < 3; j++) acc[i][j] = (f32x4){0.f, 0.f, 0.f, 0.f};

    float4 xr[2][4];     // two named register sets -> 2-iteration load flight
    short8 wr[2][3];

#define LOADN(SET, K)                                                             \
    do {                                                                          \
        _Pragma("unroll")                                                         \
        for (int p = 0; p < 4; p++)                                               \
            xr[SET][p] = *(const float4*)(xsrc + (size_t)p * (16 * EMB_D) + (K)); \
        _Pragma("unroll")                                                         \
        for (int p = 0; p < 3; p++)                                               \
            wr[SET][p] = *(const short8*)(wsrc + (size_t)p * (32 * EMB_D) + (K)); \
    } while (0)

#define STAGE(SET, BUF)                                                           \
    do {                                                                          \
        char* xb = (char*)&xsm[BUF][0];                                           \
        char* wb = (char*)&wsm[BUF][0];                                           \
        _Pragma("unroll")                                                         \
        for (int p = 0; p < 4; p++) {                                             \
            uint2v u;                                                             \
            u.x = pk2(xr[SET][p].x, xr[SET][p].y);                                \
            u.y = pk2(xr[SET][p].z, xr[SET][p].w);                                \
            *(uint2v*)(xb + xw + p * 2048) = u;                                   \
        }                                                                         \
        _Pragma("unroll")                                                         \
        for (int p = 0; p < 3; p++)                                               \
            *(short8*)(wb + wwo + p * 4096) = wr[SET][p];                         \
    } while (0)

#define COMPUTE(BUF)                                                              \
    do {                                                                          \
        const char* xb = (const char*)&xsm[BUF][0];                               \
        const char* wb = (const char*)&wsm[BUF][0];                               \
        short8 Af[2][2];                                                          \
        _Pragma("unroll")                                                         \
        for (int i = 0; i < 2; i++)                                               \
            _Pragma("unroll")                                                     \
            for (int ks = 0; ks < 2; ks++)                                        \
                Af[i][ks] = *(const short8*)(xb + ra[i][ks]);                     \
        __builtin_amdgcn_s_setprio(1);                                            \
        _Pragma("unroll")                                                         \
        for (int ks = 0; ks < 2; ks++)                                            \
            _Pragma("unroll")                                                     \
            for (int jj = 0; jj < 3; jj++) {                                      \
                const short8 Bf = *(const short8*)(wb + rb[jj][ks]);              \
                _Pragma("unroll")                                                 \
                for (int i = 0; i < 2; i++)                                       \
                    acc[i][jj] = __builtin_amdgcn_mfma_f32_16x16x32_bf16(         \
                        Af[i][ks], Bf, acc[i][jj], 0, 0, 0);                      \
            }                                                                     \
        __builtin_amdgcn_s_setprio(0);                                            \
    } while (0)

// barrier: drain own ds ops (write visibility), do NOT touch vmcnt — global
// loads stay in flight across the barrier; "memory" clobber also pins the
// loads inside their issuing iteration.
#define BARX() asm volatile("s_waitcnt lgkmcnt(0)\n\ts_barrier" ::: "memory")

    // ---- prologue: x/W(0)->set0, x/W(1)->set1, stage(0), x/W(2)->set0
    LOADN(0, 0);
    LOADN(1, 64);
    STAGE(0, 0);          // compiler: counted vmcnt wait for set0 only
    LOADN(0, 128);

    // ---- main loop: iter j = {BAR; stage x(j+1); load x(j+3); compute(j)}
    //      buffers/sets alternate by parity; loads get 2 full iterations.
#pragma clang loop unroll(disable)
    for (int j = 0; j < 28; j += 2) {
        BARX(); STAGE(1, 1); LOADN(1, (j + 3) * 64); COMPUTE(0);
        BARX(); STAGE(0, 0); LOADN(0, (j + 4) * 64); COMPUTE(1);
    }
    // ---- tail: iters 28..31 (stage x29..x31, last load x31, drain computes)
    BARX(); STAGE(1, 1); LOADN(1, 31 * 64); COMPUTE(0);   // iter 28
    BARX(); STAGE(0, 0);                    COMPUTE(1);   // iter 29
    BARX(); STAGE(1, 1);                    COMPUTE(0);   // iter 30
    BARX();                                 COMPUTE(1);   // iter 31

#undef LOADN
#undef STAGE
#undef COMPUTE
#undef BARX

    const float qscale = 0.08838834764831845f * 1.4426950408889634f; // 1/sqrt(128)*log2(e)
#pragma unroll
    for (int i = 0; i < 2; i++) {
#pragma unroll
        for (int r = 0; r < 4; r++) {
            const int row = m0 + wm * 32 + i * 16 + lq * 4 + r;   // b*T + t
            const int t = row & (T_SEQ - 1);
            const int bb = row >> 11;
#pragma unroll
            for (int j = 0; j < 3; j++) {
                const int col = ng * 96 + wn * 48 + j * 16 + l15;
                const int mat = col >> 7, mcol = col & 127;
                const float v = acc[i][j][r];
                if (mat == 2) {
                    Vt[((size_t)bb * HD_D + mcol) * T_SEQ + t] = f2bf_rne(v);
                } else {
                    const int ip = mcol >> 1;
                    const float c = rcos[t * 64 + ip];
                    const float s2 = rsin[t * 64 + ip];
                    const float pv = __shfl_xor(v, 1);
                    float rv = (mcol & 1) ? (pv * s2 + v * c) : (v * c - pv * s2);
                    if (mat == 0) {
                        rv *= qscale;
                        Qb[(size_t)row * HD_D + mcol] = f2bf_rne(rv);
                    } else {
                        Kb[(size_t)row * HD_D + mcol] = f2bf_rne(rv);
                    }
                }
            }
        }
    }
}

// ---------------------------------------------------------------------------
// Kernel 2: flash attention — R21: R18 (QBLK=32) + 2-deep K PREFETCH.
//   R18's loop loads K and consumes it IMMEDIATELY in QK^T -> full L2/L3
//   latency (~200-400 cyc) exposed once per 32-k chunk per wave. R21:
//   named double K sets (rule #20: no runtime-indexed arrays); K(c+8) is
//   issued during softmax+PV of chunk c. Chunk sequence and every MFMA
//   order are unchanged -> bit-identical output to R18. V loads stay in
//   place (latency already covered by softmax). Regs ~230 at (256,2).
// ---------------------------------------------------------------------------
__global__ __launch_bounds__(256, 2) void attn(
    const unsigned short* __restrict__ Qb, const unsigned short* __restrict__ Kb,
    const unsigned short* __restrict__ Vt, float* __restrict__ O0,
    unsigned short* __restrict__ O1, float* __restrict__ Lp)
{
    __shared__ __attribute__((aligned(16))) unsigned short O_s[4][32 * 128];   // 32 KB
    __shared__ __attribute__((aligned(16))) unsigned short P_s[4][32 * 40];    // 10 KB
    __shared__ float l_s[4][32];

    const int tid = threadIdx.x;
    const int lane = tid & 63, wave = tid >> 6;
    const int l15 = lane & 15, lq = lane >> 4;
    const int kf = lq * 8;

    const int L = blockIdx.x;
    const int g = L & 1;                         // k-group
    const int b = (L >> 1) & 3;
    const int q0 = (63 - (L >> 3)) * 32;         // heavy q-blocks first
    const int kend = q0 + 32;
    const float M2 = 16.0f;                      // static max (exp2 domain)

    const unsigned short* Qp = Qb + (size_t)(b * T_SEQ + q0) * HD_D;
    short8 aQ[2][4];
#pragma unroll
    for (int i = 0; i < 2; i++)
#pragma unroll
        for (int d = 0; d < 4; d++)
            aQ[i][d] = *(const short8*)&Qp[(size_t)(i * 16 + l15) * HD_D + d * 32 + kf];

    f32x4 acc[2][8];
#pragma unroll
    for (int i = 0; i < 2; i++)
#pragma unroll
        for (int d = 0; d < 8; d++) acc[i][d] = (f32x4){0.f, 0.f, 0.f, 0.f};
    float l_r[2][4] = {{0.f, 0.f, 0.f, 0.f}, {0.f, 0.f, 0.f, 0.f}};

    const unsigned short* Kbase = Kb + (size_t)b * T_SEQ * HD_D;
    const unsigned short* Vbase = Vt + (size_t)b * HD_D * T_SEQ;
    unsigned short* Pw = &P_s[wave][0];

    short8 KA_A[8], KA_B[8], VA[8];
    f32x4 sc[2][2];

#define LOADK(DST, C0)                                                         \
    do {                                                                       \
        const unsigned short* Kp = Kbase + (size_t)((C0) * 32) * HD_D;         \
        _Pragma("unroll")                                                      \
        for (int d = 0; d < 4; d++)                                            \
            _Pragma("unroll")                                                  \
            for (int n = 0; n < 2; n++)                                        \
                DST[d * 2 + n] =                                               \
                    *(const short8*)&Kp[(size_t)(n * 16 + l15) * HD_D + d * 32 + kf]; \
    } while (0)

#define QKSEG(KREG)                                                            \
    do {                                                                       \
        _Pragma("unroll")                                                      \
        for (int i = 0; i < 2; i++)                                            \
            _Pragma("unroll")                                                  \
            for (int n = 0; n < 2; n++) sc[i][n] = (f32x4){0.f, 0.f, 0.f, 0.f};\
        _Pragma("unroll")                                                      \
        for (int d = 0; d < 4; d++)                                            \
            _Pragma("unroll")                                                  \
            for (int i = 0; i < 2; i++)                                        \
                _Pragma("unroll")                                              \
                for (int n = 0; n < 2; n++)                                    \
                    sc[i][n] = __builtin_amdgcn_mfma_f32_16x16x32_bf16(        \
                        aQ[i][d], KREG[d * 2 + n], sc[i][n], 0, 0, 0);         \
    } while (0)

#define LOADV(C0)                                                              \
    do {                                                                       \
        _Pragma("unroll")                                                      \
        for (int d = 0; d < 8; d++)                                            \
            VA[d] = *(const short8*)                                           \
                &Vbase[(size_t)(d * 16 + l15) * T_SEQ + (C0) * 32 + kf];       \
    } while (0)

#define SMPV(C0)                                                               \
    do {                                                                       \
        const int kA = (C0) * 32;                                              \
        _Pragma("unroll")                                                      \
        for (int i = 0; i < 2; i++)                                            \
            _Pragma("unroll")                                                  \
            for (int r = 0; r < 4; r++) {                                      \
                const int q = q0 + i * 16 + lq * 4 + r;                        \
                const float p0 = ((kA + l15)      <= q) ? EXP2F(sc[i][0][r] - M2) : 0.f; \
                const float p1 = ((kA + 16 + l15) <= q) ? EXP2F(sc[i][1][r] - M2) : 0.f; \
                l_r[i][r] += p0 + p1;                                          \
                const int prow = (i * 16 + lq * 4 + r) * 40;                   \
                Pw[prow + l15]      = f2bf_fast(p0);                           \
                Pw[prow + 16 + l15] = f2bf_fast(p1);                           \
            }                                                                  \
        short8 pA[2];                                                          \
        _Pragma("unroll")                                                      \
        for (int i = 0; i < 2; i++)                                            \
            pA[i] = *(const short8*)&Pw[(i * 16 + l15) * 40 + kf];             \
        _Pragma("unroll")                                                      \
        for (int i = 0; i < 2; i++)                                            \
            _Pragma("unroll")                                                  \
            for (int d = 0; d < 8; d++)                                        \
                acc[i][d] = __builtin_amdgcn_mfma_f32_16x16x32_bf16(           \
                    pA[i], VA[d], acc[i][d], 0, 0, 0);                         \
    } while (0)

    int cc = 2 * wave + g;
    if (cc * 32 < kend) {
        LOADK(KA_A, cc);
#pragma clang loop unroll(disable)
        for (;;) {
            // ---- chunk A = cc (K prefetched)
            QKSEG(KA_A);
            LOADV(cc);
            {
                const int cB = cc + 8;
                const bool hB = (cB * 32 < kend);
                if (hB) LOADK(KA_B, cB);        // prefetch under softmax+PV
                SMPV(cc);
                if (!hB) break;
            }
            // ---- chunk B = cc + 8
            QKSEG(KA_B);
            LOADV(cc + 8);
            {
                const int cC = cc + 16;
                const bool hC = (cC * 32 < kend);
                if (hC) LOADK(KA_A, cC);        // prefetch under softmax+PV
                SMPV(cc + 8);
                if (!hC) break;
            }
            cc += 16;
        }
    }

#undef LOADK
#undef QKSEG
#undef LOADV
#undef SMPV

#pragma unroll
    for (int i = 0; i < 2; i++)
#pragma unroll
        for (int r = 0; r < 4; r++) {
            float lr = l_r[i][r];
            lr += __shfl_xor(lr, 1);
            lr += __shfl_xor(lr, 2);
            lr += __shfl_xor(lr, 4);
            lr += __shfl_xor(lr, 8);
            if (l15 == 0) l_s[wave][i * 16 + lq * 4 + r] = lr;
#pragma unroll
            for (int d = 0; d < 8; d++)
                O_s[wave][(i * 16 + lq * 4 + r) * 128 + d * 16 + l15] = f2bf_fast(acc[i][d][r]);
        }
    __syncthreads();

#pragma unroll
    for (int pass = 0; pass < 2; pass++) {
        const int row = pass * 16 + (tid >> 4);
        const int dc = (tid & 15) * 8;
        const float lt = l_s[0][row] + l_s[1][row] + l_s[2][row] + l_s[3][row];
        float o[8];
#pragma unroll
        for (int k = 0; k < 8; k++) o[k] = 0.f;
#pragma unroll
        for (int w2 = 0; w2 < 4; w2++) {
            const ushort8v pv = *(const ushort8v*)&O_s[w2][row * 128 + dc];
#pragma unroll
            for (int k = 0; k < 8; k++) o[k] += bf2f(pv[k]);
        }
        const size_t grow = (size_t)(b * T_SEQ + q0 + row);
        if (g == 0) {
            float* op = O0 + grow * HD_D + dc;
#pragma unroll
            for (int k = 0; k < 8; k++) op[k] = o[k];
        } else {
            ushort8v h;
#pragma unroll
            for (int k = 0; k < 8; k++) h[k] = f2bf_fast(o[k]);
            *(ushort8v*)&O1[grow * HD_D + dc] = h;
        }
        if ((tid & 15) == 0) Lp[g * 8192 + grow] = lt;
    }
}

// ---------------------------------------------------------------------------
// Kernel 3: combine the two k-group partials: out = (O0 + O1) / (l0 + l1)
// ---------------------------------------------------------------------------
__global__ __launch_bounds__(256) void attn_merge(
    float* __restrict__ out, const unsigned short* __restrict__ O1,
    const float* __restrict__ Lp)
{
    const int idx = blockIdx.x * 256 + threadIdx.x;   // f32x4 index (262144)
    const int row = idx >> 5;                          // 32 f32x4 per row
    f32x4 a = ((f32x4*)out)[idx];
    const ushort4v h = ((const ushort4v*)O1)[idx];
    f32x4 bv = { bf2f(h.x), bf2f(h.y), bf2f(h.z), bf2f(h.w) };
    const float inv = 1.0f / (Lp[row] + Lp[8192 + row]);
    ((f32x4*)out)[idx] = (a + bv) * inv;
}

// ---------------------------------------------------------------------------
extern "C" void kernel_launch(void* const* d_in, const int* in_sizes, int n_in,
                              void* d_out, int out_size, void* d_ws, size_t ws_size,
                              hipStream_t stream)
{
    (void)in_sizes; (void)n_in; (void)out_size; (void)ws_size;
    const float* x  = (const float*)d_in[0];
    const float* Wq = (const float*)d_in[1];
    const float* Wk = (const float*)d_in[2];
    const float* Wv = (const float*)d_in[3];
    const float* rc = (const float*)d_in[4];
    const float* rs = (const float*)d_in[5];
    // d_in[6] = additive causal mask: handled analytically, not read.
    float* out = (float*)d_out;

    char* ws = (char*)d_ws;
    unsigned short* Wt = (unsigned short*)(ws);                    // 1,572,864 B
    unsigned short* Qb = (unsigned short*)(ws + 1572864);          // 2,097,152 B
    unsigned short* Kb = (unsigned short*)(ws + 3670016);          // 2,097,152 B
    unsigned short* Vt = (unsigned short*)(ws + 5767168);          // 2,097,152 B
    unsigned short* O1 = (unsigned short*)(ws + 7864320);          // 2,097,152 B
    float*          Lp = (float*)(ws + 9961472);                   //    65,536 B

    prep_weights<<<dim3(32, 3), 256, 0, stream>>>(Wq, Wk, Wv, Wt);
    qkv_fused   <<<dim3(512),   256, 0, stream>>>(x, Wt, rc, rs, Qb, Kb, Vt);
    attn        <<<dim3(512),   256, 0, stream>>>(Qb, Kb, Vt, out, O1, Lp);
    attn_merge  <<<dim3(1024),  256, 0, stream>>>(out, O1, Lp);
}